// Round 1
// baseline (209.515 us; speedup 1.0000x reference)
//
#include <hip/hip_runtime.h>

#define CLIP_IN  1000000.0f
#define CLIP_OUT 1000000.0f

__device__ __forceinline__ float horner9(float x, const float* __restrict__ c) {
    // clip input
    float xc = fminf(fmaxf(x, -CLIP_IN), CLIP_IN);
    float r = c[8];
    r = fmaf(r, xc, c[7]);
    r = fmaf(r, xc, c[6]);
    r = fmaf(r, xc, c[5]);
    r = fmaf(r, xc, c[4]);
    r = fmaf(r, xc, c[3]);
    r = fmaf(r, xc, c[2]);
    r = fmaf(r, xc, c[1]);
    r = fmaf(r, xc, c[0]);
    // clip output
    return fminf(fmaxf(r, -CLIP_OUT), CLIP_OUT);
}

__global__ __launch_bounds__(256) void TaylorActivation_77043123355716_kernel(
        const float4* __restrict__ x4,
        const float* __restrict__ w,
        float4* __restrict__ out4,
        long long n4) {
    // coefficients: uniform address -> compiler emits scalar loads / broadcast
    float c[9];
#pragma unroll
    for (int i = 0; i < 9; ++i) c[i] = w[i];

    long long idx = (long long)blockIdx.x * blockDim.x + threadIdx.x;
    const long long stride = (long long)gridDim.x * blockDim.x;
    for (; idx < n4; idx += stride) {
        float4 v = x4[idx];
        float4 o;
        o.x = horner9(v.x, c);
        o.y = horner9(v.y, c);
        o.z = horner9(v.z, c);
        o.w = horner9(v.w, c);
        out4[idx] = o;
    }
}

__global__ void TaylorActivation_77043123355716_tail(
        const float* __restrict__ x,
        const float* __restrict__ w,
        float* __restrict__ out,
        long long start, long long n) {
    float c[9];
#pragma unroll
    for (int i = 0; i < 9; ++i) c[i] = w[i];
    long long i = start + threadIdx.x;
    if (i < n) out[i] = horner9(x[i], c);
}

extern "C" void kernel_launch(void* const* d_in, const int* in_sizes, int n_in,
                              void* d_out, int out_size, void* d_ws, size_t ws_size,
                              hipStream_t stream) {
    const float* x = (const float*)d_in[0];
    const float* w = (const float*)d_in[1];
    float* out = (float*)d_out;

    long long n = (long long)in_sizes[0];   // 16*4096*2048 = 134217728
    long long n4 = n >> 2;                  // float4 count
    long long rem = n & 3;

    int block = 256;
    long long total_blocks = (n4 + block - 1) / block;
    int grid = (int)(total_blocks < 2048 ? (total_blocks > 0 ? total_blocks : 1) : 2048);

    TaylorActivation_77043123355716_kernel<<<grid, block, 0, stream>>>(
        (const float4*)x, w, (float4*)out, n4);

    if (rem) {
        TaylorActivation_77043123355716_tail<<<1, 64, 0, stream>>>(
            x, w, out, n4 << 2, n);
    }
}

// Round 3
// 177.287 us; speedup vs baseline: 1.1818x; 1.1818x over previous
//
#include <hip/hip_runtime.h>

#define CLIP_IN  1000000.0f
#define CLIP_OUT 1000000.0f

typedef float f32x4 __attribute__((ext_vector_type(4)));

__device__ __forceinline__ float horner9(float x, const float* __restrict__ c) {
    float xc = fminf(fmaxf(x, -CLIP_IN), CLIP_IN);
    float r = c[8];
    r = fmaf(r, xc, c[7]);
    r = fmaf(r, xc, c[6]);
    r = fmaf(r, xc, c[5]);
    r = fmaf(r, xc, c[4]);
    r = fmaf(r, xc, c[3]);
    r = fmaf(r, xc, c[2]);
    r = fmaf(r, xc, c[1]);
    r = fmaf(r, xc, c[0]);
    return fminf(fmaxf(r, -CLIP_OUT), CLIP_OUT);
}

constexpr int BLOCK  = 256;
constexpr int UNROLL = 8;   // float4 per thread per tile -> 8 loads in flight

// Full tiles only: grid covers n_full_tiles exactly.
__global__ __launch_bounds__(BLOCK) void TaylorActivation_77043123355716_kernel(
        const f32x4* __restrict__ x4,
        const float* __restrict__ w,
        f32x4* __restrict__ out4) {
    float c[9];
#pragma unroll
    for (int i = 0; i < 9; ++i) c[i] = w[i];

    long long base = (long long)blockIdx.x * (BLOCK * UNROLL) + threadIdx.x;

    f32x4 v[UNROLL];
#pragma unroll
    for (int i = 0; i < UNROLL; ++i)
        v[i] = __builtin_nontemporal_load(&x4[base + (long long)i * BLOCK]);

    f32x4 o[UNROLL];
#pragma unroll
    for (int i = 0; i < UNROLL; ++i) {
        o[i].x = horner9(v[i].x, c);
        o[i].y = horner9(v[i].y, c);
        o[i].z = horner9(v[i].z, c);
        o[i].w = horner9(v[i].w, c);
    }

#pragma unroll
    for (int i = 0; i < UNROLL; ++i)
        __builtin_nontemporal_store(o[i], &out4[base + (long long)i * BLOCK]);
}

// Generic scalar remainder (handles anything past the full tiles).
__global__ __launch_bounds__(BLOCK) void TaylorActivation_77043123355716_tail(
        const float* __restrict__ x,
        const float* __restrict__ w,
        float* __restrict__ out,
        long long start, long long n) {
    float c[9];
#pragma unroll
    for (int i = 0; i < 9; ++i) c[i] = w[i];
    long long i = start + (long long)blockIdx.x * blockDim.x + threadIdx.x;
    const long long stride = (long long)gridDim.x * blockDim.x;
    for (; i < n; i += stride) out[i] = horner9(x[i], c);
}

extern "C" void kernel_launch(void* const* d_in, const int* in_sizes, int n_in,
                              void* d_out, int out_size, void* d_ws, size_t ws_size,
                              hipStream_t stream) {
    const float* x = (const float*)d_in[0];
    const float* w = (const float*)d_in[1];
    float* out = (float*)d_out;

    long long n  = (long long)in_sizes[0];      // 134217728
    long long n4 = n >> 2;                      // 33554432 float4
    const long long tile = (long long)BLOCK * UNROLL;   // 2048 float4 per block
    long long full_tiles = n4 / tile;           // 16384
    long long covered4   = full_tiles * tile;

    if (full_tiles > 0) {
        TaylorActivation_77043123355716_kernel<<<(int)full_tiles, BLOCK, 0, stream>>>(
            (const f32x4*)x, w, (f32x4*)out);
    }

    long long rem_start = covered4 << 2;        // first uncovered element
    if (rem_start < n) {
        long long rem = n - rem_start;
        int blocks = (int)((rem + BLOCK - 1) / BLOCK);
        if (blocks > 1024) blocks = 1024;
        TaylorActivation_77043123355716_tail<<<blocks, BLOCK, 0, stream>>>(
            x, w, out, rem_start, n);
    }
}